// Round 7
// baseline (274.652 us; speedup 1.0000x reference)
//
#include <hip/hip_runtime.h>
#include <hip/hip_bf16.h>

// LocalAttention B=4, L=2048, C=512, H=8, Dh=64 — round 7.
// vs round 6:
//  * w_cvt: all four W matrices fp32->bf16 once (proj A-staging = pure copy)
//  * global_load_lds width-16 staging for proj A/B and attn K/V, with the
//    XOR swizzle applied on the per-lane GLOBAL address (LDS slot order is
//    hardware-fixed: base + lane*16), so fragment reads are unchanged.
//  * attn: 128-thr blocks (2 waves x 32q), 1024 blocks, single-buffer K/V,
//    24.3KB LDS -> 6 blocks/CU (12 waves/CU) for latency hiding.
//  * proj: 64M x 128N tile, BK=64, 512 blocks.
//  * qh lives in d_out (16MB, dead until final out-proj overwrites it);
//    ws: Xt/ctx(8M) kh(8M) vh(8M) Wb(2M) = 26MB.

#define BB  4
#define LL  2048
#define CC  512
#define HH  8
#define DHH 64

typedef __attribute__((ext_vector_type(8)))  short bf16x8;   // 16 B
typedef __attribute__((ext_vector_type(4)))  short bf16x4;   // 8 B
typedef __attribute__((ext_vector_type(16))) float f32x16;   // MFMA C/D
typedef __attribute__((ext_vector_type(2)))  unsigned uint2v;
typedef __attribute__((ext_vector_type(4)))  unsigned uint4v;

using us = unsigned short;

#if __has_builtin(__builtin_amdgcn_exp2f)
#define EXP2(x) __builtin_amdgcn_exp2f(x)
#else
#define EXP2(x) __expf(0.6931471805599453f * (x))
#endif

__device__ __forceinline__ int swz(int r) { return (r + (r >> 3)) & 7; }

__device__ __forceinline__ us f2bu(float x) {   // scalar fp32->bf16 (RNE)
    unsigned u = __float_as_uint(x);
    return (us)((u + 0x7FFFu + ((u >> 16) & 1u)) >> 16);
}
__device__ __forceinline__ unsigned pk2(float a, float b) {
    return (unsigned)f2bu(a) | ((unsigned)f2bu(b) << 16);
}
__device__ __forceinline__ bf16x4 pk4(float a, float b, float c, float d) {
    uint2v u; u[0] = pk2(a, b); u[1] = pk2(c, d);
    return __builtin_bit_cast(bf16x4, u);
}

// async 16B global->LDS. lds ptr must be wave-uniform; lane i lands at
// lds + i*16.
__device__ __forceinline__ void gll16(const void* g, void* l) {
    __builtin_amdgcn_global_load_lds(
        (const __attribute__((address_space(1))) void*)(void*)g,
        (__attribute__((address_space(3))) void*)l, 16, 0, 0);
}

// ---------------------------------------------------------------------------
// 4x W fp32 [512][512] -> bf16, packed at Wb + m*CC*CC
// ---------------------------------------------------------------------------
__global__ __launch_bounds__(256) void w_cvt(const float* __restrict__ W0,
                                             const float* __restrict__ W1,
                                             const float* __restrict__ W2,
                                             const float* __restrict__ W3,
                                             us* __restrict__ Wb)
{
    const float* Ws[4] = {W0, W1, W2, W3};
    const int m = blockIdx.y;
    const float* W = Ws[m];
    const size_t idx = ((size_t)blockIdx.x * 256 + threadIdx.x) * 8;
    const float4 f0 = *(const float4*)(W + idx);
    const float4 f1 = *(const float4*)(W + idx + 4);
    uint4v u;
    u[0] = pk2(f0.x, f0.y); u[1] = pk2(f0.z, f0.w);
    u[2] = pk2(f1.x, f1.y); u[3] = pk2(f1.z, f1.w);
    *(bf16x8*)(Wb + (size_t)m * CC * CC + idx) = __builtin_bit_cast(bf16x8, u);
}

// ---------------------------------------------------------------------------
// fp32 [b][c][n] -> bf16 [b][n][c]
// ---------------------------------------------------------------------------
__global__ __launch_bounds__(256) void transpose_cvt(const float* __restrict__ X,
                                                     us* __restrict__ Xt)
{
    const int b = blockIdx.z, c0 = blockIdx.y * 64, n0 = blockIdx.x * 64;
    const int t = threadIdx.x;
    __shared__ float T[64][65];

    const float* Xb = X + ((size_t)b * CC + c0) * LL + n0;
    #pragma unroll
    for (int i = 0; i < 4; ++i) {
        const int cl = (t >> 4) + 16 * i, nl = (t & 15) * 4;
        const float4 f = *(const float4*)(Xb + (size_t)cl * LL + nl);
        T[cl][nl + 0] = f.x; T[cl][nl + 1] = f.y;
        T[cl][nl + 2] = f.z; T[cl][nl + 3] = f.w;
    }
    __syncthreads();
    us* Ot = Xt + ((size_t)b * LL + n0) * CC + c0;
    #pragma unroll
    for (int i = 0; i < 2; ++i) {
        const int nl = (t >> 3) + 32 * i, cb = (t & 7) * 8;
        uint4v u;
        #pragma unroll
        for (int j = 0; j < 4; ++j)
            u[j] = pk2(T[cb + 2 * j][nl], T[cb + 2 * j + 1][nl]);
        *(bf16x8*)(Ot + (size_t)nl * CC + cb) = __builtin_bit_cast(bf16x8, u);
    }
}

// ---------------------------------------------------------------------------
// GEMM: Y[b][o][n] = sum_c Wb[o][c]*Xt[b][n][c] + bias[o].
// Tile 64(M) x 128(N), BK=64, 256 thr = 4 waves of 32x64. gll staging.
// MODE 0: bf16 out, per-head position-major [b][h][n][64], (acc+bias)*scale
// MODE 1: bf16 out, channel-major [b][o][n]
// MODE 2: fp32 out, channel-major [b][o][n]
// ---------------------------------------------------------------------------
template <int MODE>
__global__ __launch_bounds__(256, 4) void proj_gemm(const us* __restrict__ Xt,
                                                    const us* __restrict__ Wb,
                                                    const float* __restrict__ bias,
                                                    float scale,
                                                    void* __restrict__ Yv)
{
    const int b  = blockIdx.z, n0 = blockIdx.x * 128, m0 = blockIdx.y * 64;
    const int t  = threadIdx.x, lane = t & 63, wave = t >> 6;
    const int quad2 = lane >> 5, l31 = lane & 31;
    const int lsub = lane >> 3, lbk = lane & 7;
    const int wm = (wave >> 1) * 32, wn = (wave & 1) * 64;

    __shared__ us As[64 * 64];    // [m][k] swizzled
    __shared__ us Bs[128 * 64];   // [n][k] swizzled
    __shared__ float biasS[64];

    f32x16 acc[2];
    #pragma unroll
    for (int nt = 0; nt < 2; ++nt)
        #pragma unroll
        for (int e = 0; e < 16; ++e) acc[nt][e] = 0.f;

    if (t < 64) biasS[t] = bias[m0 + t];

    const us* Xb = Xt + (size_t)b * LL * CC;

    for (int k0 = 0; k0 < CC; k0 += 64) {
        __syncthreads();                       // prev tile fully consumed
        // A: Wb bf16 64x64 (512 chunks, 2/thread). LDS slot (r, sc) gets
        // global chunk sc^swz(r) -> fragment reads see the usual swizzle.
        #pragma unroll
        for (int i = 0; i < 2; ++i) {
            const int rb = i * 32 + wave * 8;
            const int r  = rb + lsub;
            gll16(Wb + (size_t)(m0 + r) * CC + k0 + ((lbk ^ swz(r)) * 8),
                  As + rb * 64);
        }
        // B: Xt bf16 128x64 (1024 chunks, 4/thread)
        #pragma unroll
        for (int i = 0; i < 4; ++i) {
            const int rb = i * 32 + wave * 8;
            const int r  = rb + lsub;
            gll16(Xb + (size_t)(n0 + r) * CC + k0 + ((lbk ^ swz(r)) * 8),
                  Bs + rb * 64);
        }
        __syncthreads();                       // drains vmcnt -> LDS ready
        #pragma unroll
        for (int ks = 0; ks < 4; ++ks) {
            const int bk = quad2 + 2 * ks;
            const int ra = wm + l31;
            const bf16x8 af = *(const bf16x8*)(As + ra * 64 + ((bk ^ swz(ra)) * 8));
            #pragma unroll
            for (int nt = 0; nt < 2; ++nt) {
                const int rb = wn + nt * 32 + l31;
                const bf16x8 bfr = *(const bf16x8*)(Bs + rb * 64 + ((bk ^ swz(rb)) * 8));
                acc[nt] = __builtin_amdgcn_mfma_f32_32x32x16_bf16(af, bfr, acc[nt], 0, 0, 0);
            }
        }
    }

    #pragma unroll
    for (int nt = 0; nt < 2; ++nt) {
        const int nloc = wn + nt * 32 + l31;
        if (MODE == 0) {
            us* Y = (us*)Yv;
            #pragma unroll
            for (int rg2 = 0; rg2 < 4; ++rg2) {
                const int rbase = wm + 8 * rg2 + 4 * quad2;
                float v0 = (acc[nt][rg2 * 4 + 0] + biasS[rbase + 0]) * scale;
                float v1 = (acc[nt][rg2 * 4 + 1] + biasS[rbase + 1]) * scale;
                float v2 = (acc[nt][rg2 * 4 + 2] + biasS[rbase + 2]) * scale;
                float v3 = (acc[nt][rg2 * 4 + 3] + biasS[rbase + 3]) * scale;
                const int mg = m0 + rbase;
                const int h = mg >> 6, d = mg & 63;
                *(bf16x4*)(Y + (((size_t)(b * HH + h) * LL) + n0 + nloc) * DHH + d) =
                    pk4(v0, v1, v2, v3);
            }
        } else {
            #pragma unroll
            for (int reg = 0; reg < 16; ++reg) {
                const int row = (reg & 3) + 8 * (reg >> 2) + 4 * quad2;
                const int mloc = wm + row;
                const float v = (acc[nt][reg] + biasS[mloc]) * scale;
                const size_t addr = ((size_t)b * CC + m0 + mloc) * LL + n0 + nloc;
                if (MODE == 1) ((us*)Yv)[addr] = f2bu(v);
                else           ((float*)Yv)[addr] = v;
            }
        }
    }
}

// ---------------------------------------------------------------------------
// Flash attention. Block = 128 thr (2 waves), each wave owns 32 queries.
// 1024 blocks, single-buffered K/V via gll staging, 24.3KB LDS.
// S^T[64 n][32 q] = K^T Q (q pre-scaled 0.125*log2e), online softmax with
// q in the lane index, P^T -> wave-private LDS, O^T += V P^T.
// ---------------------------------------------------------------------------
__global__ __launch_bounds__(128, 4) void attn_fwd(
    const us* __restrict__ Qh,     // [b][h][l][64], pre-scaled
    const us* __restrict__ Kh,     // [b][h][l][64]
    const us* __restrict__ Vh,     // [b][512][l] channel-major
    const float* __restrict__ mask,// [b][1][L]
    us* __restrict__ ctx)          // [b][l][512]
{
    const int bh = blockIdx.x;     // 0..31
    const int b = bh >> 3, h = bh & 7;
    const int qb = blockIdx.y;     // 0..31
    const int t = threadIdx.x, lane = t & 63, wave = t >> 6;
    const int quad2 = lane >> 5, l31 = lane & 31;
    const int lsub = lane >> 3, lbk = lane & 7;
    const int qg = qb * 64 + wave * 32;      // wave's query base

    __shared__ us Ks[64 * 64];     // [n][d] swizzled
    __shared__ us Vs[64 * 64];     // [d][n] swizzled
    __shared__ us Ps[2][32 * 64];  // per-wave [q][n] swizzled
    __shared__ unsigned long long mwS[32];

    const float* mb = mask + (size_t)b * LL;
    #pragma unroll
    for (int i = 0; i < 16; ++i) {           // precompute all mask ballots
        const int tile = wave * 16 + i;
        const unsigned long long bal = __ballot(mb[tile * 64 + lane] > 0.5f);
        if (lane == 0) mwS[tile] = bal;
    }

    // Q fragments (register-resident)
    const us* Qbase = Qh + (size_t)bh * LL * DHH;
    bf16x8 qf[4];
    #pragma unroll
    for (int ks = 0; ks < 4; ++ks)
        qf[ks] = *(const bf16x8*)(Qbase + (size_t)(qg + l31) * DHH + ks * 16 + quad2 * 8);

    f32x16 of[2];
    #pragma unroll
    for (int mt = 0; mt < 2; ++mt)
        #pragma unroll
        for (int e = 0; e < 16; ++e) of[mt][e] = 0.f;
    float m_run = -3e38f, l_run = 0.f;

    const us* Kbase = Kh + (size_t)bh * LL * DHH;
    const us* Vbase = Vh + ((size_t)b * CC + h * DHH) * LL;

    for (int it = 0; it < LL / 64; ++it) {
        const int n0 = it * 64;
        __syncthreads();                     // prev Ks/Vs fully consumed
        #pragma unroll
        for (int i = 0; i < 4; ++i) {        // K: 512 chunks, 4/thread
            const int rb = i * 16 + wave * 8;
            const int r  = rb + lsub;
            gll16(Kbase + (size_t)(n0 + r) * DHH + ((lbk ^ swz(r)) * 8),
                  Ks + rb * 64);
        }
        #pragma unroll
        for (int i = 0; i < 4; ++i) {        // V
            const int rb = i * 16 + wave * 8;
            const int r  = rb + lsub;
            gll16(Vbase + (size_t)r * LL + n0 + ((lbk ^ swz(r)) * 8),
                  Vs + rb * 64);
        }
        __syncthreads();                     // vmcnt drained -> tiles ready

        // S^T = K^T Q
        f32x16 sf[2];
        #pragma unroll
        for (int mt = 0; mt < 2; ++mt)
            #pragma unroll
            for (int e = 0; e < 16; ++e) sf[mt][e] = 0.f;
        #pragma unroll
        for (int ks = 0; ks < 4; ++ks) {
            const int bk = quad2 + 2 * ks;
            #pragma unroll
            for (int mt = 0; mt < 2; ++mt) {
                const int r = mt * 32 + l31;
                const bf16x8 af = *(const bf16x8*)(Ks + r * 64 + ((bk ^ swz(r)) * 8));
                sf[mt] = __builtin_amdgcn_mfma_f32_32x32x16_bf16(af, qf[ks], sf[mt], 0, 0, 0);
            }
        }

        // online softmax (scores in log2 units; q == l31, rows are keys)
        float mx = -3e38f;
        #pragma unroll
        for (int mt = 0; mt < 2; ++mt)
            #pragma unroll
            for (int e = 0; e < 16; ++e) mx = fmaxf(mx, sf[mt][e]);
        mx = fmaxf(mx, __shfl_xor(mx, 32, 64));
        const float mnew = fmaxf(m_run, mx);
        const float alpha = EXP2(m_run - mnew);
        const unsigned long long mw = mwS[it];
        float ps = 0.f;
        #pragma unroll
        for (int mt = 0; mt < 2; ++mt)
            #pragma unroll
            for (int rg2 = 0; rg2 < 4; ++rg2) {
                float p[4];
                #pragma unroll
                for (int j = 0; j < 4; ++j)
                    p[j] = EXP2(sf[mt][rg2 * 4 + j] - mnew);
                if (mw != 0xFFFFFFFFFFFFFFFFull) {
                    #pragma unroll
                    for (int j = 0; j < 4; ++j) {
                        const int row = 32 * mt + 8 * rg2 + 4 * quad2 + j;
                        p[j] = ((mw >> row) & 1ull) ? p[j] : 0.f;
                    }
                }
                ps += (p[0] + p[1]) + (p[2] + p[3]);
                const int bk = 4 * mt + rg2;
                *(bf16x4*)(Ps[wave] + l31 * 64 + ((bk ^ swz(l31)) * 8) + quad2 * 4) =
                    pk4(p[0], p[1], p[2], p[3]);
            }
        ps += __shfl_xor(ps, 32, 64);
        l_run = l_run * alpha + ps;
        m_run = mnew;
        #pragma unroll
        for (int mt = 0; mt < 2; ++mt)
            #pragma unroll
            for (int e = 0; e < 16; ++e) of[mt][e] *= alpha;

        // O^T += V P^T  (Ps wave-private: in-wave LDS ordering suffices)
        #pragma unroll
        for (int ks = 0; ks < 4; ++ks) {
            const int bk = quad2 + 2 * ks;
            const bf16x8 pf = *(const bf16x8*)(Ps[wave] + l31 * 64 + ((bk ^ swz(l31)) * 8));
            #pragma unroll
            for (int mt = 0; mt < 2; ++mt) {
                const int r = mt * 32 + l31;
                const bf16x8 vf = *(const bf16x8*)(Vs + r * 64 + ((bk ^ swz(r)) * 8));
                of[mt] = __builtin_amdgcn_mfma_f32_32x32x16_bf16(vf, pf, of[mt], 0, 0, 0);
            }
        }
    }

    // epilogue: ctx[b][q][h*64+d] = O^T[d][q] / l_run
    us* Cb = ctx + (size_t)b * LL * CC;
    const float inv = 1.0f / l_run;
    const int q = qg + l31;
    #pragma unroll
    for (int mt = 0; mt < 2; ++mt)
        #pragma unroll
        for (int rg2 = 0; rg2 < 4; ++rg2) {
            const int d = 32 * mt + 8 * rg2 + 4 * quad2;
            *(bf16x4*)(Cb + (size_t)q * CC + h * DHH + d) =
                pk4(of[mt][rg2 * 4 + 0] * inv, of[mt][rg2 * 4 + 1] * inv,
                    of[mt][rg2 * 4 + 2] * inv, of[mt][rg2 * 4 + 3] * inv);
        }
}

// ---------------------------------------------------------------------------
extern "C" void kernel_launch(void* const* d_in, const int* in_sizes, int n_in,
                              void* d_out, int out_size, void* d_ws, size_t ws_size,
                              hipStream_t stream)
{
    const float* q    = (const float*)d_in[0];
    const float* k    = (const float*)d_in[1];
    const float* v    = (const float*)d_in[2];
    const float* mask = (const float*)d_in[3];
    const float* Wq   = (const float*)d_in[4];
    const float* bq   = (const float*)d_in[5];
    const float* Wk   = (const float*)d_in[6];
    const float* bk   = (const float*)d_in[7];
    const float* Wv   = (const float*)d_in[8];
    const float* bv   = (const float*)d_in[9];
    const float* Wout = (const float*)d_in[10];
    const float* bout = (const float*)d_in[11];

    const size_t TSZ = (size_t)BB * CC * LL;   // 4,194,304 elements (8 MB bf16)
    us* base = (us*)d_ws;
    us* Xt   = base;                // [0,8M)  also ctx after v-proj
    us* kh   = base + TSZ;          // [8M,16M)
    us* vh   = base + 2 * TSZ;      // [16M,24M)
    us* Wb   = base + 3 * TSZ;      // [24M,26M): 4 x 512x512 bf16
    us* ctx  = Xt;
    us* qh   = (us*)d_out;          // d_out (16MB fp32) is dead until the
                                    // final out-proj overwrites it

    const float SCALE_Q = 0.125f * 1.4426950408889634f;  // softmax scale * log2e

    const dim3 wg(CC * CC / (256 * 8), 4);
    const dim3 tg(LL / 64, CC / 64, BB), tb(256);
    const dim3 gg(LL / 128, CC / 64, BB), gb(256);

    w_cvt<<<wg, 256, 0, stream>>>(Wq, Wk, Wv, Wout, Wb);

    transpose_cvt<<<tg, tb, 0, stream>>>(q, Xt);
    proj_gemm<0><<<gg, gb, 0, stream>>>(Xt, Wb + 0 * CC * CC, bq, SCALE_Q, (void*)qh);
    transpose_cvt<<<tg, tb, 0, stream>>>(k, Xt);
    proj_gemm<0><<<gg, gb, 0, stream>>>(Xt, Wb + 1 * CC * CC, bk, 1.0f, (void*)kh);
    transpose_cvt<<<tg, tb, 0, stream>>>(v, Xt);
    proj_gemm<1><<<gg, gb, 0, stream>>>(Xt, Wb + 2 * CC * CC, bv, 1.0f, (void*)vh);

    attn_fwd<<<dim3(HH * BB, LL / 64), 128, 0, stream>>>(qh, kh, vh, mask, ctx);

    proj_gemm<2><<<gg, gb, 0, stream>>>(ctx, Wb + 3 * CC * CC, bout, 1.0f, d_out);
}